// Round 3
// baseline (651.969 us; speedup 1.0000x reference)
//
#include <hip/hip_runtime.h>
#include <hip/hip_bf16.h>

// DT loss: trilinear lookup of 1M points into a 704x704x64 fp32 distance grid,
// outputs [mean, dist[N]].
// R1: 96us, FETCH=259MB, VALUBusy 3%.
// R2: 4x per-wave MLP + 0.5x occupancy => identical 94us / 0.072 lines/cy/CU
//     => hard per-CU pending-miss cap (~64 lines / ~900cy latency). Only fix:
//     fewer misses (line reuse) or lower latency (L2 hits).
// R3: counting-sort points by 32x32-cell xy bucket (484 buckets, ~2066 pts,
//     ~250KB grid footprint each -> L2-resident), XCD-contiguous block swizzle
//     in the gather so a bucket's lines stay in one XCD's L2.

#define GH 704
#define GW 704
#define GD 64

#define BSH   5            // bucket = 32x32 cells (3.2m x 3.2m)
#define NBX   22           // ceil(704/32)
#define NBUCK (NBX * NBX)  // 484

// ---------------- K1: histogram + key computation ----------------
__global__ __launch_bounds__(256) void k_hist(
    const float* __restrict__ pc1, const float* __restrict__ flow,
    const float* __restrict__ grid_min, const int* __restrict__ grid_factor,
    unsigned* __restrict__ keys, unsigned* __restrict__ work, int N)
{
    __shared__ unsigned lh[NBUCK];
    for (int t = threadIdx.x; t < NBUCK; t += blockDim.x) lh[t] = 0;
    __syncthreads();

    const int i = blockIdx.x * blockDim.x + threadIdx.x;
    if (i < N) {
        const float gf = (float)(*grid_factor);
        float sx = (pc1[3 * i + 0] + flow[3 * i + 0] - grid_min[0]) * gf;
        float sy = (pc1[3 * i + 1] + flow[3 * i + 1] - grid_min[1]) * gf;
        sx = fminf(fmaxf(sx, 0.0f), (float)(GH - 1));
        sy = fminf(fmaxf(sy, 0.0f), (float)(GW - 1));
        const int x0 = (int)sx;
        const int y0 = (int)sy;
        const unsigned key = (unsigned)((x0 >> BSH) * NBX + (y0 >> BSH));
        keys[i] = key;
        atomicAdd(&lh[key], 1u);
    }
    __syncthreads();
    for (int t = threadIdx.x; t < NBUCK; t += blockDim.x) {
        const unsigned c = lh[t];
        if (c) atomicAdd(&work[t], c);
    }
}

// ---------------- K2: exclusive scan of 484 bucket counts ----------------
__global__ __launch_bounds__(512) void k_scan(unsigned* __restrict__ work)
{
    __shared__ unsigned a[512], b[512];
    const int t = threadIdx.x;
    a[t] = (t < NBUCK) ? work[t] : 0u;
    __syncthreads();
    unsigned* src = a;
    unsigned* dst = b;
    for (int off = 1; off < 512; off <<= 1) {
        unsigned v = src[t];
        if (t >= off) v += src[t - off];
        dst[t] = v;
        __syncthreads();
        unsigned* tmp = src; src = dst; dst = tmp;
    }
    if (t < NBUCK) work[t] = (t == 0) ? 0u : src[t - 1];
}

// ---------------- K3: scatter payload into sorted order ----------------
__global__ __launch_bounds__(256) void k_scatter(
    const float* __restrict__ pc1, const float* __restrict__ flow,
    const float* __restrict__ grid_min, const int* __restrict__ grid_factor,
    const unsigned* __restrict__ keys, unsigned* __restrict__ work,
    float4* __restrict__ payload, int N)
{
    const int i = blockIdx.x * blockDim.x + threadIdx.x;
    if (i >= N) return;
    const float gf = (float)(*grid_factor);
    float sx = (pc1[3 * i + 0] + flow[3 * i + 0] - grid_min[0]) * gf;
    float sy = (pc1[3 * i + 1] + flow[3 * i + 1] - grid_min[1]) * gf;
    float sz = (pc1[3 * i + 2] + flow[3 * i + 2] - grid_min[2]) * gf;
    sx = fminf(fmaxf(sx, 0.0f), (float)(GH - 1));
    sy = fminf(fmaxf(sy, 0.0f), (float)(GW - 1));
    sz = fminf(fmaxf(sz, 0.0f), (float)(GD - 1));
    const unsigned pos = atomicAdd(&work[keys[i]], 1u);
    payload[pos] = make_float4(sx, sy, sz, __uint_as_float((unsigned)i));
}

// ---------------- K4: locality-ordered gather ----------------
#define K4PTS 4
__global__ __launch_bounds__(256) void k_gather(
    const float4* __restrict__ payload, const float* __restrict__ grid,
    float* __restrict__ out, int N, int nlb /* logical blocks, %8==0 */)
{
    // XCD-contiguous swizzle: blocks on the same XCD (blockIdx%8) get a
    // contiguous logical range of the sorted array -> bucket lines stay in
    // one XCD's L2.
    const int per = nlb >> 3;
    const int logical = (blockIdx.x & 7) * per + (blockIdx.x >> 3);
    const int base = logical * (256 * K4PTS) + threadIdx.x;

    // Phase 1: load sorted payloads (coalesced float4)
    float sx[K4PTS], sy[K4PTS], sz[K4PTS];
    unsigned idx[K4PTS];
    bool act[K4PTS];
    #pragma unroll
    for (int j = 0; j < K4PTS; ++j) {
        const int i = base + j * 256;
        act[j] = (i < N);
        const float4 p = payload[act[j] ? i : 0];
        sx[j] = p.x; sy[j] = p.y; sz[j] = p.z;
        idx[j] = __float_as_uint(p.w);
    }

    // Phase 2: issue all corner gathers
    float wx[K4PTS], wy[K4PTS], wz[K4PTS];
    float c000[K4PTS], c001[K4PTS], c010[K4PTS], c011[K4PTS];
    float c100[K4PTS], c101[K4PTS], c110[K4PTS], c111[K4PTS];
    #pragma unroll
    for (int j = 0; j < K4PTS; ++j) {
        const int x0 = (int)sx[j];
        const int y0 = (int)sy[j];
        const int z0 = (int)sz[j];
        const int x1 = min(x0 + 1, GH - 1);
        const int y1 = min(y0 + 1, GW - 1);
        const int z1 = min(z0 + 1, GD - 1);
        wx[j] = sx[j] - (float)x0;
        wy[j] = sy[j] - (float)y0;
        wz[j] = sz[j] - (float)z0;
        const float* p00 = grid + ((size_t)x0 * GW + (size_t)y0) * GD;
        const float* p01 = grid + ((size_t)x0 * GW + (size_t)y1) * GD;
        const float* p10 = grid + ((size_t)x1 * GW + (size_t)y0) * GD;
        const float* p11 = grid + ((size_t)x1 * GW + (size_t)y1) * GD;
        c000[j] = p00[z0]; c001[j] = p00[z1];
        c010[j] = p01[z0]; c011[j] = p01[z1];
        c100[j] = p10[z0]; c101[j] = p10[z1];
        c110[j] = p11[z0]; c111[j] = p11[z1];
    }

    // Phase 3: lerp + scatter-store + accumulate
    float acc = 0.0f;
    #pragma unroll
    for (int j = 0; j < K4PTS; ++j) {
        const float c00 = c000[j] * (1.0f - wz[j]) + c001[j] * wz[j];
        const float c01 = c010[j] * (1.0f - wz[j]) + c011[j] * wz[j];
        const float c10 = c100[j] * (1.0f - wz[j]) + c101[j] * wz[j];
        const float c11 = c110[j] * (1.0f - wz[j]) + c111[j] * wz[j];
        const float c0 = c00 * (1.0f - wy[j]) + c01 * wy[j];
        const float c1 = c10 * (1.0f - wy[j]) + c11 * wy[j];
        const float v  = c0 * (1.0f - wx[j]) + c1 * wx[j];
        if (act[j]) {
            out[1 + idx[j]] = v;
            acc += v;
        }
    }

    // Mean: wave64 shuffle -> LDS -> one atomic/block
    float s = acc;
    #pragma unroll
    for (int off = 32; off > 0; off >>= 1)
        s += __shfl_down(s, off, 64);

    __shared__ float wsum[4];
    const int lane = threadIdx.x & 63;
    const int wid  = threadIdx.x >> 6;
    if (lane == 0) wsum[wid] = s;
    __syncthreads();
    if (threadIdx.x == 0) {
        const float part = wsum[0] + wsum[1] + wsum[2] + wsum[3];
        atomicAdd(out, part * (1.0f / (float)N));
    }
}

// ---------------- Fallback: direct kernel (R2) ----------------
__global__ __launch_bounds__(256) void dt_loss_direct(
    const float* __restrict__ pc1, const float* __restrict__ flow,
    const float* __restrict__ grid, const float* __restrict__ grid_min,
    const int* __restrict__ grid_factor, float* __restrict__ out, int N)
{
    const int i = blockIdx.x * blockDim.x + threadIdx.x;
    float val = 0.0f;
    if (i < N) {
        const float gf = (float)(*grid_factor);
        float sx = (pc1[3 * i + 0] + flow[3 * i + 0] - grid_min[0]) * gf;
        float sy = (pc1[3 * i + 1] + flow[3 * i + 1] - grid_min[1]) * gf;
        float sz = (pc1[3 * i + 2] + flow[3 * i + 2] - grid_min[2]) * gf;
        sx = fminf(fmaxf(sx, 0.0f), (float)(GH - 1));
        sy = fminf(fmaxf(sy, 0.0f), (float)(GW - 1));
        sz = fminf(fmaxf(sz, 0.0f), (float)(GD - 1));
        const int x0 = (int)sx, y0 = (int)sy, z0 = (int)sz;
        const int x1 = min(x0 + 1, GH - 1);
        const int y1 = min(y0 + 1, GW - 1);
        const int z1 = min(z0 + 1, GD - 1);
        const float wx = sx - x0, wy = sy - y0, wz = sz - z0;
        const float* p00 = grid + ((size_t)x0 * GW + (size_t)y0) * GD;
        const float* p01 = grid + ((size_t)x0 * GW + (size_t)y1) * GD;
        const float* p10 = grid + ((size_t)x1 * GW + (size_t)y0) * GD;
        const float* p11 = grid + ((size_t)x1 * GW + (size_t)y1) * GD;
        const float c00 = p00[z0] * (1 - wz) + p00[z1] * wz;
        const float c01 = p01[z0] * (1 - wz) + p01[z1] * wz;
        const float c10 = p10[z0] * (1 - wz) + p10[z1] * wz;
        const float c11 = p11[z0] * (1 - wz) + p11[z1] * wz;
        const float c0 = c00 * (1 - wy) + c01 * wy;
        const float c1 = c10 * (1 - wy) + c11 * wy;
        val = c0 * (1 - wx) + c1 * wx;
        out[1 + i] = val;
    }
    float s = val;
    #pragma unroll
    for (int off = 32; off > 0; off >>= 1) s += __shfl_down(s, off, 64);
    __shared__ float wsum[4];
    if ((threadIdx.x & 63) == 0) wsum[threadIdx.x >> 6] = s;
    __syncthreads();
    if (threadIdx.x == 0)
        atomicAdd(out, (wsum[0] + wsum[1] + wsum[2] + wsum[3]) * (1.0f / (float)N));
}

extern "C" void kernel_launch(void* const* d_in, const int* in_sizes, int n_in,
                              void* d_out, int out_size, void* d_ws, size_t ws_size,
                              hipStream_t stream) {
    const float* pc1         = (const float*)d_in[0];
    const float* flow        = (const float*)d_in[1];
    const float* grid        = (const float*)d_in[2];
    const float* grid_min    = (const float*)d_in[3];
    const int*   grid_factor = (const int*)d_in[4];
    float* out = (float*)d_out;

    const int N = in_sizes[0] / 3;  // pc1 is [1, N, 3]
    hipMemsetAsync(d_out, 0, sizeof(float), stream);

    // ws layout: [0,2048) work counters | [4096, 4096+4N) keys | then payload
    const size_t keys_off    = 4096;
    const size_t payload_off = keys_off + (size_t)4 * N;  // 16B-aligned for N%4==0
    const size_t need = payload_off + (size_t)16 * N + 64;

    if (ws_size < need || (payload_off % 16) != 0) {
        // Fallback: direct gather (R2 performance)
        const int block = 256;
        dt_loss_direct<<<(N + block - 1) / block, block, 0, stream>>>(
            pc1, flow, grid, grid_min, grid_factor, out, N);
        return;
    }

    unsigned* work    = (unsigned*)d_ws;
    unsigned* keys    = (unsigned*)((char*)d_ws + keys_off);
    float4*   payload = (float4*)((char*)d_ws + payload_off);

    hipMemsetAsync(d_ws, 0, 2048, stream);

    const int block = 256;
    const int nb = (N + block - 1) / block;

    k_hist<<<nb, block, 0, stream>>>(pc1, flow, grid_min, grid_factor, keys, work, N);
    k_scan<<<1, 512, 0, stream>>>(work);
    k_scatter<<<nb, block, 0, stream>>>(pc1, flow, grid_min, grid_factor, keys, work, payload, N);

    // gather: 1024 points per block, pad logical block count to multiple of 8
    int nlb = (N + 1024 - 1) / 1024;
    nlb = (nlb + 7) & ~7;
    k_gather<<<nlb, block, 0, stream>>>(payload, grid, out, N, nlb);
}

// Round 4
// 274.290 us; speedup vs baseline: 2.3769x; 2.3769x over previous
//
#include <hip/hip_runtime.h>
#include <hip/hip_bf16.h>

// DT loss: trilinear lookup of 1M points into a 704x704x64 fp32 distance grid,
// outputs [mean, dist[N]].
// R1: direct, 96us, FETCH=259MB (3.8 miss-lines/pt), VALUBusy 3%.
// R2: 4x MLP, 0.5x occupancy => same 94us => per-CU pending-miss cap
//     (~64 lines / ~900cy) — only fewer misses or lower latency helps.
// R3: atomic counting sort => k_scatter 335us: 1M device atomics over 484
//     addresses serialize at the cross-XCD coherence point. Sort idea untested.
// R4: atomic-free counting sort (per-block histograms + two-level scan;
//     LDS-only rank atomics). Gather unchanged (sorted order, XCD swizzle).

#define GH 704
#define GW 704
#define GD 64

#define BSH   5            // bucket = 32x32 cells (3.2m x 3.2m)
#define NBX   22           // ceil(704/32)
#define NBUCK (NBX * NBX)  // 484
#define NBLK  256          // sort blocks (chunks)

// ---------------- K1: per-block histogram (no global atomics) ----------------
__global__ __launch_bounds__(256) void k_hist(
    const float* __restrict__ pc1, const float* __restrict__ flow,
    const float* __restrict__ grid_min, const int* __restrict__ grid_factor,
    unsigned* __restrict__ hist /* [NBLK][NBUCK] */, int N, int chunk)
{
    __shared__ unsigned lh[NBUCK];
    for (int t = threadIdx.x; t < NBUCK; t += 256) lh[t] = 0;
    __syncthreads();

    const float gf  = (float)(*grid_factor);
    const float gmx = grid_min[0];
    const float gmy = grid_min[1];

    const int start = blockIdx.x * chunk;
    const int end   = min(start + chunk, N);
    for (int i = start + threadIdx.x; i < end; i += 256) {
        float sx = (pc1[3 * i + 0] + flow[3 * i + 0] - gmx) * gf;
        float sy = (pc1[3 * i + 1] + flow[3 * i + 1] - gmy) * gf;
        sx = fminf(fmaxf(sx, 0.0f), (float)(GH - 1));
        sy = fminf(fmaxf(sy, 0.0f), (float)(GW - 1));
        const unsigned key = (unsigned)(((int)sx >> BSH) * NBX + ((int)sy >> BSH));
        atomicAdd(&lh[key], 1u);   // LDS atomic — cheap
    }
    __syncthreads();
    for (int t = threadIdx.x; t < NBUCK; t += 256)
        hist[blockIdx.x * NBUCK + t] = lh[t];
}

// ---- K2a: per-bucket exclusive scan across the 256 blocks (484 blocks) ----
__global__ __launch_bounds__(256) void k_scan_blocks(
    unsigned* __restrict__ hist, unsigned* __restrict__ totals)
{
    __shared__ unsigned a[256], b[256];
    const int B  = threadIdx.x;   // source block
    const int bk = blockIdx.x;    // bucket
    const unsigned v = hist[B * NBUCK + bk];
    a[B] = v;
    __syncthreads();
    unsigned* src = a; unsigned* dst = b;
    for (int off = 1; off < 256; off <<= 1) {
        unsigned x = src[B];
        if (B >= off) x += src[B - off];
        dst[B] = x;
        __syncthreads();
        unsigned* t = src; src = dst; dst = t;
    }
    hist[B * NBUCK + bk] = src[B] - v;          // exclusive prefix within bucket
    if (B == 255) totals[bk] = src[255];        // bucket total
}

// ---- K2b: exclusive scan of the 484 bucket totals (1 block) ----
__global__ __launch_bounds__(512) void k_scan_buckets(unsigned* __restrict__ totals)
{
    __shared__ unsigned a[512], b[512];
    const int t = threadIdx.x;
    const unsigned v = (t < NBUCK) ? totals[t] : 0u;
    a[t] = v;
    __syncthreads();
    unsigned* src = a; unsigned* dst = b;
    for (int off = 1; off < 512; off <<= 1) {
        unsigned x = src[t];
        if (t >= off) x += src[t - off];
        dst[t] = x;
        __syncthreads();
        unsigned* tmp = src; src = dst; dst = tmp;
    }
    if (t < NBUCK) totals[t] = src[t] - v;      // exclusive bucket base
}

// ---------------- K3: scatter via LDS ranks (no global atomics) ----------------
__global__ __launch_bounds__(256) void k_scatter(
    const float* __restrict__ pc1, const float* __restrict__ flow,
    const float* __restrict__ grid_min, const int* __restrict__ grid_factor,
    const unsigned* __restrict__ hist, const unsigned* __restrict__ bbase,
    float4* __restrict__ payload, int N, int chunk)
{
    __shared__ unsigned cur[NBUCK];
    for (int t = threadIdx.x; t < NBUCK; t += 256)
        cur[t] = hist[blockIdx.x * NBUCK + t] + bbase[t];
    __syncthreads();

    const float gf  = (float)(*grid_factor);
    const float gmx = grid_min[0];
    const float gmy = grid_min[1];
    const float gmz = grid_min[2];

    const int start = blockIdx.x * chunk;
    const int end   = min(start + chunk, N);
    for (int i = start + threadIdx.x; i < end; i += 256) {
        float sx = (pc1[3 * i + 0] + flow[3 * i + 0] - gmx) * gf;
        float sy = (pc1[3 * i + 1] + flow[3 * i + 1] - gmy) * gf;
        float sz = (pc1[3 * i + 2] + flow[3 * i + 2] - gmz) * gf;
        sx = fminf(fmaxf(sx, 0.0f), (float)(GH - 1));
        sy = fminf(fmaxf(sy, 0.0f), (float)(GW - 1));
        sz = fminf(fmaxf(sz, 0.0f), (float)(GD - 1));
        const unsigned key = (unsigned)(((int)sx >> BSH) * NBX + ((int)sy >> BSH));
        const unsigned pos = atomicAdd(&cur[key], 1u);   // LDS atomic
        payload[pos] = make_float4(sx, sy, sz, __uint_as_float((unsigned)i));
    }
}

// ---------------- K4: locality-ordered gather ----------------
#define K4PTS 4
__global__ __launch_bounds__(256) void k_gather(
    const float4* __restrict__ payload, const float* __restrict__ grid,
    float* __restrict__ out, int N, int nlb /* logical blocks, %8==0 */)
{
    // XCD-contiguous swizzle: blocks on the same XCD (blockIdx%8) get a
    // contiguous logical range of the sorted array.
    const int per = nlb >> 3;
    const int logical = (blockIdx.x & 7) * per + (blockIdx.x >> 3);
    const int base = logical * (256 * K4PTS) + threadIdx.x;

    float sx[K4PTS], sy[K4PTS], sz[K4PTS];
    unsigned idx[K4PTS];
    bool act[K4PTS];
    #pragma unroll
    for (int j = 0; j < K4PTS; ++j) {
        const int i = base + j * 256;
        act[j] = (i < N);
        const float4 p = payload[act[j] ? i : 0];
        sx[j] = p.x; sy[j] = p.y; sz[j] = p.z;
        idx[j] = __float_as_uint(p.w);
    }

    float wx[K4PTS], wy[K4PTS], wz[K4PTS];
    float c000[K4PTS], c001[K4PTS], c010[K4PTS], c011[K4PTS];
    float c100[K4PTS], c101[K4PTS], c110[K4PTS], c111[K4PTS];
    #pragma unroll
    for (int j = 0; j < K4PTS; ++j) {
        const int x0 = (int)sx[j];
        const int y0 = (int)sy[j];
        const int z0 = (int)sz[j];
        const int x1 = min(x0 + 1, GH - 1);
        const int y1 = min(y0 + 1, GW - 1);
        const int z1 = min(z0 + 1, GD - 1);
        wx[j] = sx[j] - (float)x0;
        wy[j] = sy[j] - (float)y0;
        wz[j] = sz[j] - (float)z0;
        const float* p00 = grid + ((size_t)x0 * GW + (size_t)y0) * GD;
        const float* p01 = grid + ((size_t)x0 * GW + (size_t)y1) * GD;
        const float* p10 = grid + ((size_t)x1 * GW + (size_t)y0) * GD;
        const float* p11 = grid + ((size_t)x1 * GW + (size_t)y1) * GD;
        c000[j] = p00[z0]; c001[j] = p00[z1];
        c010[j] = p01[z0]; c011[j] = p01[z1];
        c100[j] = p10[z0]; c101[j] = p10[z1];
        c110[j] = p11[z0]; c111[j] = p11[z1];
    }

    float acc = 0.0f;
    #pragma unroll
    for (int j = 0; j < K4PTS; ++j) {
        const float c00 = c000[j] * (1.0f - wz[j]) + c001[j] * wz[j];
        const float c01 = c010[j] * (1.0f - wz[j]) + c011[j] * wz[j];
        const float c10 = c100[j] * (1.0f - wz[j]) + c101[j] * wz[j];
        const float c11 = c110[j] * (1.0f - wz[j]) + c111[j] * wz[j];
        const float c0 = c00 * (1.0f - wy[j]) + c01 * wy[j];
        const float c1 = c10 * (1.0f - wy[j]) + c11 * wy[j];
        const float v  = c0 * (1.0f - wx[j]) + c1 * wx[j];
        if (act[j]) {
            out[1 + idx[j]] = v;
            acc += v;
        }
    }

    float s = acc;
    #pragma unroll
    for (int off = 32; off > 0; off >>= 1)
        s += __shfl_down(s, off, 64);

    __shared__ float wsum[4];
    const int lane = threadIdx.x & 63;
    const int wid  = threadIdx.x >> 6;
    if (lane == 0) wsum[wid] = s;
    __syncthreads();
    if (threadIdx.x == 0) {
        const float part = wsum[0] + wsum[1] + wsum[2] + wsum[3];
        atomicAdd(out, part * (1.0f / (float)N));
    }
}

// ---------------- Fallback: direct kernel (R2 performance) ----------------
__global__ __launch_bounds__(256) void dt_loss_direct(
    const float* __restrict__ pc1, const float* __restrict__ flow,
    const float* __restrict__ grid, const float* __restrict__ grid_min,
    const int* __restrict__ grid_factor, float* __restrict__ out, int N)
{
    const int i = blockIdx.x * blockDim.x + threadIdx.x;
    float val = 0.0f;
    if (i < N) {
        const float gf = (float)(*grid_factor);
        float sx = (pc1[3 * i + 0] + flow[3 * i + 0] - grid_min[0]) * gf;
        float sy = (pc1[3 * i + 1] + flow[3 * i + 1] - grid_min[1]) * gf;
        float sz = (pc1[3 * i + 2] + flow[3 * i + 2] - grid_min[2]) * gf;
        sx = fminf(fmaxf(sx, 0.0f), (float)(GH - 1));
        sy = fminf(fmaxf(sy, 0.0f), (float)(GW - 1));
        sz = fminf(fmaxf(sz, 0.0f), (float)(GD - 1));
        const int x0 = (int)sx, y0 = (int)sy, z0 = (int)sz;
        const int x1 = min(x0 + 1, GH - 1);
        const int y1 = min(y0 + 1, GW - 1);
        const int z1 = min(z0 + 1, GD - 1);
        const float wx = sx - x0, wy = sy - y0, wz = sz - z0;
        const float* p00 = grid + ((size_t)x0 * GW + (size_t)y0) * GD;
        const float* p01 = grid + ((size_t)x0 * GW + (size_t)y1) * GD;
        const float* p10 = grid + ((size_t)x1 * GW + (size_t)y0) * GD;
        const float* p11 = grid + ((size_t)x1 * GW + (size_t)y1) * GD;
        const float c00 = p00[z0] * (1 - wz) + p00[z1] * wz;
        const float c01 = p01[z0] * (1 - wz) + p01[z1] * wz;
        const float c10 = p10[z0] * (1 - wz) + p10[z1] * wz;
        const float c11 = p11[z0] * (1 - wz) + p11[z1] * wz;
        const float c0 = c00 * (1 - wy) + c01 * wy;
        const float c1 = c10 * (1 - wy) + c11 * wy;
        val = c0 * (1 - wx) + c1 * wx;
        out[1 + i] = val;
    }
    float s = val;
    #pragma unroll
    for (int off = 32; off > 0; off >>= 1) s += __shfl_down(s, off, 64);
    __shared__ float wsum[4];
    if ((threadIdx.x & 63) == 0) wsum[threadIdx.x >> 6] = s;
    __syncthreads();
    if (threadIdx.x == 0)
        atomicAdd(out, (wsum[0] + wsum[1] + wsum[2] + wsum[3]) * (1.0f / (float)N));
}

extern "C" void kernel_launch(void* const* d_in, const int* in_sizes, int n_in,
                              void* d_out, int out_size, void* d_ws, size_t ws_size,
                              hipStream_t stream) {
    const float* pc1         = (const float*)d_in[0];
    const float* flow        = (const float*)d_in[1];
    const float* grid        = (const float*)d_in[2];
    const float* grid_min    = (const float*)d_in[3];
    const int*   grid_factor = (const int*)d_in[4];
    float* out = (float*)d_out;

    const int N = in_sizes[0] / 3;  // pc1 is [1, N, 3]
    hipMemsetAsync(d_out, 0, sizeof(float), stream);

    // ws layout: hist[NBLK][NBUCK] @0 (496KB) | totals @512KB | payload @1MB
    const size_t totals_off  = 512 * 1024;
    const size_t payload_off = 1024 * 1024;
    const size_t need = payload_off + (size_t)16 * N + 64;

    if (ws_size < need) {
        const int block = 256;
        dt_loss_direct<<<(N + block - 1) / block, block, 0, stream>>>(
            pc1, flow, grid, grid_min, grid_factor, out, N);
        return;
    }

    unsigned* hist    = (unsigned*)d_ws;
    unsigned* totals  = (unsigned*)((char*)d_ws + totals_off);
    float4*   payload = (float4*)((char*)d_ws + payload_off);

    const int chunk = (N + NBLK - 1) / NBLK;

    k_hist<<<NBLK, 256, 0, stream>>>(pc1, flow, grid_min, grid_factor, hist, N, chunk);
    k_scan_blocks<<<NBUCK, 256, 0, stream>>>(hist, totals);
    k_scan_buckets<<<1, 512, 0, stream>>>(totals);
    k_scatter<<<NBLK, 256, 0, stream>>>(pc1, flow, grid_min, grid_factor,
                                        hist, totals, payload, N, chunk);

    int nlb = (N + 1024 - 1) / 1024;   // 1024 points per gather block
    nlb = (nlb + 7) & ~7;
    k_gather<<<nlb, 256, 0, stream>>>(payload, grid, out, N, nlb);
}

// Round 5
// 273.093 us; speedup vs baseline: 2.3874x; 1.0044x over previous
//
#include <hip/hip_runtime.h>
#include <hip/hip_bf16.h>

// DT loss: trilinear lookup of 1M points into a 704x704x64 fp32 distance grid,
// outputs [mean, dist[N]].
// R1: direct, 96us, FETCH=259MB, VALUBusy 3%.
// R2: 4x MLP, 0.5x occupancy => same 94us => per-CU pending-miss cap ~0.072
//     lines/cy/CU (~64 lines / ~900cy).
// R3: global-atomic sort => scatter 335us (cross-XCD atomic serialization).
// R4: atomic-free counting sort; gather FETCH 259->103MB (~compulsory) but
//     only 83us: 977 blocks -> 29% occupancy, latency-bound, miss rate 0.032
//     lines/cy/CU (under cap). Sort phases ~40us (scalar strided loads).
// R5: gather PTS=2 (1954 blocks, ~30 waves/CU) to re-saturate the miss cap
//     (predict ~40-48us); LDS-staged float4 loads in hist/scatter (~halve sort).

#define GH 704
#define GW 704
#define GD 64

#define BSH   5            // bucket = 32x32 cells (3.2m x 3.2m)
#define NBX   22           // ceil(704/32)
#define NBUCK (NBX * NBX)  // 484
#define NBLK  256          // sort blocks (chunks)
#define TILE  1024         // points staged per LDS tile (must be %4)

// ---------------- K1: per-block histogram, LDS-staged loads ----------------
__global__ __launch_bounds__(256) void k_hist(
    const float* __restrict__ pc1, const float* __restrict__ flow,
    const float* __restrict__ grid_min, const int* __restrict__ grid_factor,
    unsigned* __restrict__ hist /* [NBLK][NBUCK] */, int N, int chunk)
{
    __shared__ unsigned lh[NBUCK];
    __shared__ float lp[TILE * 3];
    __shared__ float lf[TILE * 3];
    for (int t = threadIdx.x; t < NBUCK; t += 256) lh[t] = 0;
    __syncthreads();

    const float gf  = (float)(*grid_factor);
    const float gmx = grid_min[0];
    const float gmy = grid_min[1];

    const int start = blockIdx.x * chunk;        // chunk % 4 == 0 -> 16B aligned
    const int end   = min(start + chunk, N);

    for (int t0 = start; t0 < end; t0 += TILE) {
        const int cnt = min(TILE, end - t0);     // %4 == 0 (chunk%4==0, N%4==0)
        const int n4  = (cnt * 3) >> 2;
        const float4* p4 = (const float4*)(pc1 + 3 * (size_t)t0);
        const float4* f4 = (const float4*)(flow + 3 * (size_t)t0);
        for (int k = threadIdx.x; k < n4; k += 256) {
            ((float4*)lp)[k] = p4[k];
            ((float4*)lf)[k] = f4[k];
        }
        __syncthreads();
        for (int j = threadIdx.x; j < cnt; j += 256) {
            float sx = (lp[3 * j + 0] + lf[3 * j + 0] - gmx) * gf;
            float sy = (lp[3 * j + 1] + lf[3 * j + 1] - gmy) * gf;
            sx = fminf(fmaxf(sx, 0.0f), (float)(GH - 1));
            sy = fminf(fmaxf(sy, 0.0f), (float)(GW - 1));
            const unsigned key = (unsigned)(((int)sx >> BSH) * NBX + ((int)sy >> BSH));
            atomicAdd(&lh[key], 1u);   // LDS atomic
        }
        __syncthreads();
    }
    for (int t = threadIdx.x; t < NBUCK; t += 256)
        hist[blockIdx.x * NBUCK + t] = lh[t];
}

// ---- K2a: per-bucket exclusive scan across the 256 blocks (484 blocks) ----
__global__ __launch_bounds__(256) void k_scan_blocks(
    unsigned* __restrict__ hist, unsigned* __restrict__ totals)
{
    __shared__ unsigned a[256], b[256];
    const int B  = threadIdx.x;   // source block
    const int bk = blockIdx.x;    // bucket
    const unsigned v = hist[B * NBUCK + bk];
    a[B] = v;
    __syncthreads();
    unsigned* src = a; unsigned* dst = b;
    for (int off = 1; off < 256; off <<= 1) {
        unsigned x = src[B];
        if (B >= off) x += src[B - off];
        dst[B] = x;
        __syncthreads();
        unsigned* t = src; src = dst; dst = t;
    }
    hist[B * NBUCK + bk] = src[B] - v;          // exclusive prefix within bucket
    if (B == 255) totals[bk] = src[255];        // bucket total
}

// ---- K2b: exclusive scan of the 484 bucket totals (1 block) ----
__global__ __launch_bounds__(512) void k_scan_buckets(unsigned* __restrict__ totals)
{
    __shared__ unsigned a[512], b[512];
    const int t = threadIdx.x;
    const unsigned v = (t < NBUCK) ? totals[t] : 0u;
    a[t] = v;
    __syncthreads();
    unsigned* src = a; unsigned* dst = b;
    for (int off = 1; off < 512; off <<= 1) {
        unsigned x = src[t];
        if (t >= off) x += src[t - off];
        dst[t] = x;
        __syncthreads();
        unsigned* tmp = src; src = dst; dst = tmp;
    }
    if (t < NBUCK) totals[t] = src[t] - v;      // exclusive bucket base
}

// ---------------- K3: scatter via LDS ranks, LDS-staged loads ----------------
__global__ __launch_bounds__(256) void k_scatter(
    const float* __restrict__ pc1, const float* __restrict__ flow,
    const float* __restrict__ grid_min, const int* __restrict__ grid_factor,
    const unsigned* __restrict__ hist, const unsigned* __restrict__ bbase,
    float4* __restrict__ payload, int N, int chunk)
{
    __shared__ unsigned cur[NBUCK];
    __shared__ float lp[TILE * 3];
    __shared__ float lf[TILE * 3];
    for (int t = threadIdx.x; t < NBUCK; t += 256)
        cur[t] = hist[blockIdx.x * NBUCK + t] + bbase[t];
    __syncthreads();

    const float gf  = (float)(*grid_factor);
    const float gmx = grid_min[0];
    const float gmy = grid_min[1];
    const float gmz = grid_min[2];

    const int start = blockIdx.x * chunk;
    const int end   = min(start + chunk, N);

    for (int t0 = start; t0 < end; t0 += TILE) {
        const int cnt = min(TILE, end - t0);
        const int n4  = (cnt * 3) >> 2;
        const float4* p4 = (const float4*)(pc1 + 3 * (size_t)t0);
        const float4* f4 = (const float4*)(flow + 3 * (size_t)t0);
        for (int k = threadIdx.x; k < n4; k += 256) {
            ((float4*)lp)[k] = p4[k];
            ((float4*)lf)[k] = f4[k];
        }
        __syncthreads();
        for (int j = threadIdx.x; j < cnt; j += 256) {
            float sx = (lp[3 * j + 0] + lf[3 * j + 0] - gmx) * gf;
            float sy = (lp[3 * j + 1] + lf[3 * j + 1] - gmy) * gf;
            float sz = (lp[3 * j + 2] + lf[3 * j + 2] - gmz) * gf;
            sx = fminf(fmaxf(sx, 0.0f), (float)(GH - 1));
            sy = fminf(fmaxf(sy, 0.0f), (float)(GW - 1));
            sz = fminf(fmaxf(sz, 0.0f), (float)(GD - 1));
            const unsigned key = (unsigned)(((int)sx >> BSH) * NBX + ((int)sy >> BSH));
            const unsigned pos = atomicAdd(&cur[key], 1u);   // LDS atomic
            payload[pos] = make_float4(sx, sy, sz, __uint_as_float((unsigned)(t0 + j)));
        }
        __syncthreads();
    }
}

// ---------------- K4: locality-ordered gather ----------------
#define K4PTS 2
__global__ __launch_bounds__(256) void k_gather(
    const float4* __restrict__ payload, const float* __restrict__ grid,
    float* __restrict__ out, int N, int nlb /* logical blocks, %8==0 */)
{
    // XCD-contiguous swizzle: blocks on the same XCD (blockIdx%8) get a
    // contiguous logical range of the sorted array.
    const int per = nlb >> 3;
    const int logical = (blockIdx.x & 7) * per + (blockIdx.x >> 3);
    const int base = logical * (256 * K4PTS) + threadIdx.x;

    float sx[K4PTS], sy[K4PTS], sz[K4PTS];
    unsigned idx[K4PTS];
    bool act[K4PTS];
    #pragma unroll
    for (int j = 0; j < K4PTS; ++j) {
        const int i = base + j * 256;
        act[j] = (i < N);
        const float4 p = payload[act[j] ? i : 0];
        sx[j] = p.x; sy[j] = p.y; sz[j] = p.z;
        idx[j] = __float_as_uint(p.w);
    }

    float wx[K4PTS], wy[K4PTS], wz[K4PTS];
    float c000[K4PTS], c001[K4PTS], c010[K4PTS], c011[K4PTS];
    float c100[K4PTS], c101[K4PTS], c110[K4PTS], c111[K4PTS];
    #pragma unroll
    for (int j = 0; j < K4PTS; ++j) {
        const int x0 = (int)sx[j];
        const int y0 = (int)sy[j];
        const int z0 = (int)sz[j];
        const int x1 = min(x0 + 1, GH - 1);
        const int y1 = min(y0 + 1, GW - 1);
        const int z1 = min(z0 + 1, GD - 1);
        wx[j] = sx[j] - (float)x0;
        wy[j] = sy[j] - (float)y0;
        wz[j] = sz[j] - (float)z0;
        const float* p00 = grid + ((size_t)x0 * GW + (size_t)y0) * GD;
        const float* p01 = grid + ((size_t)x0 * GW + (size_t)y1) * GD;
        const float* p10 = grid + ((size_t)x1 * GW + (size_t)y0) * GD;
        const float* p11 = grid + ((size_t)x1 * GW + (size_t)y1) * GD;
        c000[j] = p00[z0]; c001[j] = p00[z1];
        c010[j] = p01[z0]; c011[j] = p01[z1];
        c100[j] = p10[z0]; c101[j] = p10[z1];
        c110[j] = p11[z0]; c111[j] = p11[z1];
    }

    float acc = 0.0f;
    #pragma unroll
    for (int j = 0; j < K4PTS; ++j) {
        const float c00 = c000[j] * (1.0f - wz[j]) + c001[j] * wz[j];
        const float c01 = c010[j] * (1.0f - wz[j]) + c011[j] * wz[j];
        const float c10 = c100[j] * (1.0f - wz[j]) + c101[j] * wz[j];
        const float c11 = c110[j] * (1.0f - wz[j]) + c111[j] * wz[j];
        const float c0 = c00 * (1.0f - wy[j]) + c01 * wy[j];
        const float c1 = c10 * (1.0f - wy[j]) + c11 * wy[j];
        const float v  = c0 * (1.0f - wx[j]) + c1 * wx[j];
        if (act[j]) {
            out[1 + idx[j]] = v;
            acc += v;
        }
    }

    float s = acc;
    #pragma unroll
    for (int off = 32; off > 0; off >>= 1)
        s += __shfl_down(s, off, 64);

    __shared__ float wsum[4];
    const int lane = threadIdx.x & 63;
    const int wid  = threadIdx.x >> 6;
    if (lane == 0) wsum[wid] = s;
    __syncthreads();
    if (threadIdx.x == 0) {
        const float part = wsum[0] + wsum[1] + wsum[2] + wsum[3];
        atomicAdd(out, part * (1.0f / (float)N));
    }
}

// ---------------- Fallback: direct kernel (R2 performance) ----------------
__global__ __launch_bounds__(256) void dt_loss_direct(
    const float* __restrict__ pc1, const float* __restrict__ flow,
    const float* __restrict__ grid, const float* __restrict__ grid_min,
    const int* __restrict__ grid_factor, float* __restrict__ out, int N)
{
    const int i = blockIdx.x * blockDim.x + threadIdx.x;
    float val = 0.0f;
    if (i < N) {
        const float gf = (float)(*grid_factor);
        float sx = (pc1[3 * i + 0] + flow[3 * i + 0] - grid_min[0]) * gf;
        float sy = (pc1[3 * i + 1] + flow[3 * i + 1] - grid_min[1]) * gf;
        float sz = (pc1[3 * i + 2] + flow[3 * i + 2] - grid_min[2]) * gf;
        sx = fminf(fmaxf(sx, 0.0f), (float)(GH - 1));
        sy = fminf(fmaxf(sy, 0.0f), (float)(GW - 1));
        sz = fminf(fmaxf(sz, 0.0f), (float)(GD - 1));
        const int x0 = (int)sx, y0 = (int)sy, z0 = (int)sz;
        const int x1 = min(x0 + 1, GH - 1);
        const int y1 = min(y0 + 1, GW - 1);
        const int z1 = min(z0 + 1, GD - 1);
        const float wx = sx - x0, wy = sy - y0, wz = sz - z0;
        const float* p00 = grid + ((size_t)x0 * GW + (size_t)y0) * GD;
        const float* p01 = grid + ((size_t)x0 * GW + (size_t)y1) * GD;
        const float* p10 = grid + ((size_t)x1 * GW + (size_t)y0) * GD;
        const float* p11 = grid + ((size_t)x1 * GW + (size_t)y1) * GD;
        const float c00 = p00[z0] * (1 - wz) + p00[z1] * wz;
        const float c01 = p01[z0] * (1 - wz) + p01[z1] * wz;
        const float c10 = p10[z0] * (1 - wz) + p10[z1] * wz;
        const float c11 = p11[z0] * (1 - wz) + p11[z1] * wz;
        const float c0 = c00 * (1 - wy) + c01 * wy;
        const float c1 = c10 * (1 - wy) + c11 * wy;
        val = c0 * (1 - wx) + c1 * wx;
        out[1 + i] = val;
    }
    float s = val;
    #pragma unroll
    for (int off = 32; off > 0; off >>= 1) s += __shfl_down(s, off, 64);
    __shared__ float wsum[4];
    if ((threadIdx.x & 63) == 0) wsum[threadIdx.x >> 6] = s;
    __syncthreads();
    if (threadIdx.x == 0)
        atomicAdd(out, (wsum[0] + wsum[1] + wsum[2] + wsum[3]) * (1.0f / (float)N));
}

extern "C" void kernel_launch(void* const* d_in, const int* in_sizes, int n_in,
                              void* d_out, int out_size, void* d_ws, size_t ws_size,
                              hipStream_t stream) {
    const float* pc1         = (const float*)d_in[0];
    const float* flow        = (const float*)d_in[1];
    const float* grid        = (const float*)d_in[2];
    const float* grid_min    = (const float*)d_in[3];
    const int*   grid_factor = (const int*)d_in[4];
    float* out = (float*)d_out;

    const int N = in_sizes[0] / 3;  // pc1 is [1, N, 3]
    hipMemsetAsync(d_out, 0, sizeof(float), stream);

    // ws layout: hist[NBLK][NBUCK] @0 (496KB) | totals @512KB | payload @1MB
    const size_t totals_off  = 512 * 1024;
    const size_t payload_off = 1024 * 1024;
    const size_t need = payload_off + (size_t)16 * N + 64;

    // chunk must be %4 for float4-aligned LDS staging; N must be %4 too.
    int chunk = (N + NBLK - 1) / NBLK;
    chunk = (chunk + 3) & ~3;

    if (ws_size < need || (N & 3) != 0) {
        const int block = 256;
        dt_loss_direct<<<(N + block - 1) / block, block, 0, stream>>>(
            pc1, flow, grid, grid_min, grid_factor, out, N);
        return;
    }

    unsigned* hist    = (unsigned*)d_ws;
    unsigned* totals  = (unsigned*)((char*)d_ws + totals_off);
    float4*   payload = (float4*)((char*)d_ws + payload_off);

    k_hist<<<NBLK, 256, 0, stream>>>(pc1, flow, grid_min, grid_factor, hist, N, chunk);
    k_scan_blocks<<<NBUCK, 256, 0, stream>>>(hist, totals);
    k_scan_buckets<<<1, 512, 0, stream>>>(totals);
    k_scatter<<<NBLK, 256, 0, stream>>>(pc1, flow, grid_min, grid_factor,
                                        hist, totals, payload, N, chunk);

    int nlb = (N + (256 * K4PTS) - 1) / (256 * K4PTS);   // 512 pts per gather block
    nlb = (nlb + 7) & ~7;
    k_gather<<<nlb, 256, 0, stream>>>(payload, grid, out, N, nlb);
}

// Round 6
// 250.950 us; speedup vs baseline: 2.5980x; 1.0882x over previous
//
#include <hip/hip_runtime.h>
#include <hip/hip_bf16.h>

// DT loss: trilinear lookup of 1M points into a 704x704x64 fp32 distance grid,
// outputs [mean, dist[N]].
// R1: direct, 96us, FETCH=259MB.
// R2: 4x MLP, 0.5x occupancy => same 94us.
// R3: global-atomic sort => 335us scatter (cross-XCD atomic serialization).
// R4: atomic-free sort; gather FETCH 103MB but 84us (29% occ).
// R5: occ 54%, FETCH 84MB, still 84us. Conclusion: the invariant across all
//     rounds is ~9.3M divergent lane-transactions at ~4.6 cy/txn/CU — the cap
//     is TA/per-CU request throughput, NOT HBM lines and NOT occupancy.
// R6: halve gather txns: one 16B load per (x,y) corner covers both z0,z1
//     (zb = min(z0&~1,60), cndmask select). Drop the sort (saves ~38us of
//     kernels); coalesced out stores; LDS-staged point loads.
//     Predict ~45us single kernel.

#define GH 704
#define GW 704
#define GD 64
#define PTS  2
#define TILE 512   // PTS * 256 points per block

// 16B vector with 8B alignment guarantee (zb is even => 8B-aligned address).
typedef float uf4 __attribute__((vector_size(16), aligned(8)));

__device__ __forceinline__ float sel4(uf4 f, int d) {
    // f[d] for d in [0,3] via 3 cndmasks
    const float a = (d & 2) ? f[2] : f[0];
    const float b = (d & 2) ? f[3] : f[1];
    return (d & 1) ? b : a;
}

__global__ __launch_bounds__(256) void dt_loss_f4(
    const float* __restrict__ pc1, const float* __restrict__ flow,
    const float* __restrict__ grid, const float* __restrict__ grid_min,
    const int* __restrict__ grid_factor, float* __restrict__ out, int N)
{
    __shared__ float lp[TILE * 3];
    __shared__ float lf[TILE * 3];

    const int start = blockIdx.x * TILE;
    const int cnt   = min(TILE, N - start);     // N%4==0 => cnt%4==0
    const int n4    = (cnt * 3) >> 2;
    const float4* p4 = (const float4*)(pc1 + 3 * (size_t)start);
    const float4* f4 = (const float4*)(flow + 3 * (size_t)start);
    for (int k = threadIdx.x; k < n4; k += 256) {
        ((float4*)lp)[k] = p4[k];
        ((float4*)lf)[k] = f4[k];
    }
    __syncthreads();

    const float gf  = (float)(*grid_factor);
    const float gmx = grid_min[0];
    const float gmy = grid_min[1];
    const float gmz = grid_min[2];

    // ---- Phase 1: addresses + issue all 4*PTS 16B gathers ----
    uf4 q00[PTS], q01[PTS], q10[PTS], q11[PTS];
    float wx[PTS], wy[PTS], wz[PTS];
    int  d0[PTS];
    bool act[PTS];
    #pragma unroll
    for (int j = 0; j < PTS; ++j) {
        const int l = threadIdx.x + j * 256;
        act[j] = (start + l) < N;
        const int ll = act[j] ? l : 0;
        float sx = (lp[3 * ll + 0] + lf[3 * ll + 0] - gmx) * gf;
        float sy = (lp[3 * ll + 1] + lf[3 * ll + 1] - gmy) * gf;
        float sz = (lp[3 * ll + 2] + lf[3 * ll + 2] - gmz) * gf;
        sx = fminf(fmaxf(sx, 0.0f), (float)(GH - 1));
        sy = fminf(fmaxf(sy, 0.0f), (float)(GW - 1));
        sz = fminf(fmaxf(sz, 0.0f), (float)(GD - 1));

        const int x0 = (int)sx;             // >=0, floor == trunc
        const int y0 = (int)sy;
        const int z0 = (int)sz;
        const int x1 = min(x0 + 1, GH - 1);
        const int y1 = min(y0 + 1, GW - 1);
        wx[j] = sx - (float)x0;
        wy[j] = sy - (float)y0;
        wz[j] = sz - (float)z0;

        // 16B window [zb, zb+3] always contains z0 and min(z0+1,63);
        // zb even (8B aligned), zb+3 <= 63 (never crosses the row).
        const int zb = min(z0 & ~1, GD - 4);
        d0[j] = z0 - zb;                    // 0..3

        const float* r00 = grid + (((x0 * GW) + y0) << 6) + zb;
        const float* r01 = grid + (((x0 * GW) + y1) << 6) + zb;
        const float* r10 = grid + (((x1 * GW) + y0) << 6) + zb;
        const float* r11 = grid + (((x1 * GW) + y1) << 6) + zb;
        q00[j] = *(const uf4*)r00;
        q01[j] = *(const uf4*)r01;
        q10[j] = *(const uf4*)r10;
        q11[j] = *(const uf4*)r11;
    }

    // ---- Phase 2: select + lerp + coalesced store ----
    float acc = 0.0f;
    #pragma unroll
    for (int j = 0; j < PTS; ++j) {
        const int dz0 = d0[j];
        const int dz1 = min(dz0 + 1, 3);    // z0==63 => wz==0, value unused
        const float c000 = sel4(q00[j], dz0), c001 = sel4(q00[j], dz1);
        const float c010 = sel4(q01[j], dz0), c011 = sel4(q01[j], dz1);
        const float c100 = sel4(q10[j], dz0), c101 = sel4(q10[j], dz1);
        const float c110 = sel4(q11[j], dz0), c111 = sel4(q11[j], dz1);

        const float c00 = c000 * (1.0f - wz[j]) + c001 * wz[j];
        const float c01 = c010 * (1.0f - wz[j]) + c011 * wz[j];
        const float c10 = c100 * (1.0f - wz[j]) + c101 * wz[j];
        const float c11 = c110 * (1.0f - wz[j]) + c111 * wz[j];
        const float c0  = c00 * (1.0f - wy[j]) + c01 * wy[j];
        const float c1  = c10 * (1.0f - wy[j]) + c11 * wy[j];
        const float v   = c0 * (1.0f - wx[j]) + c1 * wx[j];
        if (act[j]) {
            out[1 + start + threadIdx.x + j * 256] = v;   // coalesced
            acc += v;
        }
    }

    // ---- Mean: wave64 shuffle -> LDS -> one atomic/block ----
    float s = acc;
    #pragma unroll
    for (int off = 32; off > 0; off >>= 1)
        s += __shfl_down(s, off, 64);

    __shared__ float wsum[4];
    const int lane = threadIdx.x & 63;
    const int wid  = threadIdx.x >> 6;
    if (lane == 0) wsum[wid] = s;
    __syncthreads();
    if (threadIdx.x == 0) {
        const float part = wsum[0] + wsum[1] + wsum[2] + wsum[3];
        atomicAdd(out, part * (1.0f / (float)N));
    }
}

// ---------------- Fallback: scalar direct kernel (any N) ----------------
__global__ __launch_bounds__(256) void dt_loss_direct(
    const float* __restrict__ pc1, const float* __restrict__ flow,
    const float* __restrict__ grid, const float* __restrict__ grid_min,
    const int* __restrict__ grid_factor, float* __restrict__ out, int N)
{
    const int i = blockIdx.x * blockDim.x + threadIdx.x;
    float val = 0.0f;
    if (i < N) {
        const float gf = (float)(*grid_factor);
        float sx = (pc1[3 * i + 0] + flow[3 * i + 0] - grid_min[0]) * gf;
        float sy = (pc1[3 * i + 1] + flow[3 * i + 1] - grid_min[1]) * gf;
        float sz = (pc1[3 * i + 2] + flow[3 * i + 2] - grid_min[2]) * gf;
        sx = fminf(fmaxf(sx, 0.0f), (float)(GH - 1));
        sy = fminf(fmaxf(sy, 0.0f), (float)(GW - 1));
        sz = fminf(fmaxf(sz, 0.0f), (float)(GD - 1));
        const int x0 = (int)sx, y0 = (int)sy, z0 = (int)sz;
        const int x1 = min(x0 + 1, GH - 1);
        const int y1 = min(y0 + 1, GW - 1);
        const int z1 = min(z0 + 1, GD - 1);
        const float wx = sx - x0, wy = sy - y0, wz = sz - z0;
        const float* p00 = grid + ((size_t)x0 * GW + (size_t)y0) * GD;
        const float* p01 = grid + ((size_t)x0 * GW + (size_t)y1) * GD;
        const float* p10 = grid + ((size_t)x1 * GW + (size_t)y0) * GD;
        const float* p11 = grid + ((size_t)x1 * GW + (size_t)y1) * GD;
        const float c00 = p00[z0] * (1 - wz) + p00[z1] * wz;
        const float c01 = p01[z0] * (1 - wz) + p01[z1] * wz;
        const float c10 = p10[z0] * (1 - wz) + p10[z1] * wz;
        const float c11 = p11[z0] * (1 - wz) + p11[z1] * wz;
        const float c0 = c00 * (1 - wy) + c01 * wy;
        const float c1 = c10 * (1 - wy) + c11 * wy;
        val = c0 * (1 - wx) + c1 * wx;
        out[1 + i] = val;
    }
    float s = val;
    #pragma unroll
    for (int off = 32; off > 0; off >>= 1) s += __shfl_down(s, off, 64);
    __shared__ float wsum[4];
    if ((threadIdx.x & 63) == 0) wsum[threadIdx.x >> 6] = s;
    __syncthreads();
    if (threadIdx.x == 0)
        atomicAdd(out, (wsum[0] + wsum[1] + wsum[2] + wsum[3]) * (1.0f / (float)N));
}

extern "C" void kernel_launch(void* const* d_in, const int* in_sizes, int n_in,
                              void* d_out, int out_size, void* d_ws, size_t ws_size,
                              hipStream_t stream) {
    const float* pc1         = (const float*)d_in[0];
    const float* flow        = (const float*)d_in[1];
    const float* grid        = (const float*)d_in[2];
    const float* grid_min    = (const float*)d_in[3];
    const int*   grid_factor = (const int*)d_in[4];
    float* out = (float*)d_out;

    const int N = in_sizes[0] / 3;  // pc1 is [1, N, 3]
    hipMemsetAsync(d_out, 0, sizeof(float), stream);

    if ((N & 3) != 0) {
        dt_loss_direct<<<(N + 255) / 256, 256, 0, stream>>>(
            pc1, flow, grid, grid_min, grid_factor, out, N);
        return;
    }

    const int nb = (N + TILE - 1) / TILE;
    dt_loss_f4<<<nb, 256, 0, stream>>>(
        pc1, flow, grid, grid_min, grid_factor, out, N);
}

// Round 7
// 249.854 us; speedup vs baseline: 2.6094x; 1.0044x over previous
//
#include <hip/hip_runtime.h>
#include <hip/hip_bf16.h>

// DT loss: trilinear lookup of 1M points into a 704x704x64 fp32 distance grid,
// outputs [mean, dist[N]].
// R1: direct, 96us, FETCH=259MB.       R2: 4x MLP => same 94us.
// R3: global-atomic sort => 335us.     R4/R5: sorted, FETCH 84-103MB, still 84us.
// R6: 16B@8B-align z-windows => split into 2x8B => 8 req/pt => 100us.
// UNIFIED MODEL: chip-wide post-coalescing line-request throughput ~85-100G/s
//   (same cap explains 6.3TB/s streaming ceiling: 100G lines/s x 64B).
//   Unique line-requests per instruction is the only currency; hit/miss,
//   occupancy, HBM bytes are secondary.
// R7: per corner ONE 16B-ALIGNED float4 window at zb=z0&~3 (dword offset
//   %4==0 -> guaranteed single global_load_dwordx4). Covers z0,z0+1 except
//   z0%4==3 && z0<63 (25% of lanes) -> predicated extra dword (exec-masked
//   lanes issue nothing). ~5.7 req/pt vs 8.4 => predict 62-68us.

#define GH 704
#define GW 704
#define GD 64
#define PTS  2
#define TILE 512   // PTS * 256 points per block

__device__ __forceinline__ float sel4(float4 f, int d) {
    // f[d] for d in [0,3] via 3 cndmasks
    const float a = (d & 2) ? f.z : f.x;
    const float b = (d & 2) ? f.w : f.y;
    return (d & 1) ? b : a;
}

__global__ __launch_bounds__(256) void dt_loss_zwin(
    const float* __restrict__ pc1, const float* __restrict__ flow,
    const float* __restrict__ grid, const float* __restrict__ grid_min,
    const int* __restrict__ grid_factor, float* __restrict__ out, int N)
{
    __shared__ float lp[TILE * 3];
    __shared__ float lf[TILE * 3];

    const int start = blockIdx.x * TILE;
    const int cnt   = min(TILE, N - start);     // N%4==0 => cnt%4==0
    const int n4    = (cnt * 3) >> 2;
    const float4* p4 = (const float4*)(pc1 + 3 * (size_t)start);
    const float4* f4 = (const float4*)(flow + 3 * (size_t)start);
    for (int k = threadIdx.x; k < n4; k += 256) {
        ((float4*)lp)[k] = p4[k];
        ((float4*)lf)[k] = f4[k];
    }
    __syncthreads();

    const float gf  = (float)(*grid_factor);
    const float gmx = grid_min[0];
    const float gmy = grid_min[1];
    const float gmz = grid_min[2];

    // ---- Phase 1: addresses + issue all gathers (16B-aligned windows) ----
    float4 q00[PTS], q01[PTS], q10[PTS], q11[PTS];
    float  e00[PTS], e01[PTS], e10[PTS], e11[PTS];
    float  wx[PTS], wy[PTS], wz[PTS];
    int    dz0[PTS];
    bool   need[PTS], act[PTS];
    #pragma unroll
    for (int j = 0; j < PTS; ++j) {
        const int l = threadIdx.x + j * 256;
        act[j] = (start + l) < N;
        const int ll = act[j] ? l : 0;
        float sx = (lp[3 * ll + 0] + lf[3 * ll + 0] - gmx) * gf;
        float sy = (lp[3 * ll + 1] + lf[3 * ll + 1] - gmy) * gf;
        float sz = (lp[3 * ll + 2] + lf[3 * ll + 2] - gmz) * gf;
        sx = fminf(fmaxf(sx, 0.0f), (float)(GH - 1));
        sy = fminf(fmaxf(sy, 0.0f), (float)(GW - 1));
        sz = fminf(fmaxf(sz, 0.0f), (float)(GD - 1));

        const int x0 = (int)sx;             // >=0, floor == trunc
        const int y0 = (int)sy;
        const int z0 = (int)sz;
        const int x1 = min(x0 + 1, GH - 1);
        const int y1 = min(y0 + 1, GW - 1);
        wx[j] = sx - (float)x0;
        wy[j] = sy - (float)y0;
        wz[j] = sz - (float)z0;

        const int zb = z0 & ~3;             // 16B-aligned window [zb, zb+3]
        dz0[j] = z0 & 3;

        // dword offsets: ((x*GW+y)<<6) %16==0, zb%4==0 -> full float4 natural
        // alignment -> guaranteed single global_load_dwordx4.
        const float* r00 = grid + (((x0 * GW) + y0) << 6) + zb;
        const float* r01 = grid + (((x0 * GW) + y1) << 6) + zb;
        const float* r10 = grid + (((x1 * GW) + y0) << 6) + zb;
        const float* r11 = grid + (((x1 * GW) + y1) << 6) + zb;
        q00[j] = *(const float4*)r00;
        q01[j] = *(const float4*)r01;
        q10[j] = *(const float4*)r10;
        q11[j] = *(const float4*)r11;

        // z0+1 falls outside the window only for z0%4==3 (and z0<63):
        // predicated extra dword at zb+4 (inactive lanes issue no requests).
        need[j] = (dz0[j] == 3) && (z0 < GD - 1);
        e00[j] = e01[j] = e10[j] = e11[j] = 0.0f;
        if (need[j]) {
            e00[j] = r00[4];
            e01[j] = r01[4];
            e10[j] = r10[4];
            e11[j] = r11[4];
        }
    }

    // ---- Phase 2: select + lerp + coalesced store ----
    float acc = 0.0f;
    #pragma unroll
    for (int j = 0; j < PTS; ++j) {
        const int d0 = dz0[j];
        const int d1 = (d0 < 3) ? d0 + 1 : 3;   // z0==63 -> wz==0, same slot ok
        const float c000 = sel4(q00[j], d0);
        const float c010 = sel4(q01[j], d0);
        const float c100 = sel4(q10[j], d0);
        const float c110 = sel4(q11[j], d0);
        const float c001 = need[j] ? e00[j] : sel4(q00[j], d1);
        const float c011 = need[j] ? e01[j] : sel4(q01[j], d1);
        const float c101 = need[j] ? e10[j] : sel4(q10[j], d1);
        const float c111 = need[j] ? e11[j] : sel4(q11[j], d1);

        const float c00 = c000 * (1.0f - wz[j]) + c001 * wz[j];
        const float c01 = c010 * (1.0f - wz[j]) + c011 * wz[j];
        const float c10 = c100 * (1.0f - wz[j]) + c101 * wz[j];
        const float c11 = c110 * (1.0f - wz[j]) + c111 * wz[j];
        const float c0  = c00 * (1.0f - wy[j]) + c01 * wy[j];
        const float c1  = c10 * (1.0f - wy[j]) + c11 * wy[j];
        const float v   = c0 * (1.0f - wx[j]) + c1 * wx[j];
        if (act[j]) {
            out[1 + start + threadIdx.x + j * 256] = v;   // coalesced
            acc += v;
        }
    }

    // ---- Mean: wave64 shuffle -> LDS -> one atomic/block ----
    float s = acc;
    #pragma unroll
    for (int off = 32; off > 0; off >>= 1)
        s += __shfl_down(s, off, 64);

    __shared__ float wsum[4];
    const int lane = threadIdx.x & 63;
    const int wid  = threadIdx.x >> 6;
    if (lane == 0) wsum[wid] = s;
    __syncthreads();
    if (threadIdx.x == 0) {
        const float part = wsum[0] + wsum[1] + wsum[2] + wsum[3];
        atomicAdd(out, part * (1.0f / (float)N));
    }
}

// ---------------- Fallback: scalar direct kernel (any N) ----------------
__global__ __launch_bounds__(256) void dt_loss_direct(
    const float* __restrict__ pc1, const float* __restrict__ flow,
    const float* __restrict__ grid, const float* __restrict__ grid_min,
    const int* __restrict__ grid_factor, float* __restrict__ out, int N)
{
    const int i = blockIdx.x * blockDim.x + threadIdx.x;
    float val = 0.0f;
    if (i < N) {
        const float gf = (float)(*grid_factor);
        float sx = (pc1[3 * i + 0] + flow[3 * i + 0] - grid_min[0]) * gf;
        float sy = (pc1[3 * i + 1] + flow[3 * i + 1] - grid_min[1]) * gf;
        float sz = (pc1[3 * i + 2] + flow[3 * i + 2] - grid_min[2]) * gf;
        sx = fminf(fmaxf(sx, 0.0f), (float)(GH - 1));
        sy = fminf(fmaxf(sy, 0.0f), (float)(GW - 1));
        sz = fminf(fmaxf(sz, 0.0f), (float)(GD - 1));
        const int x0 = (int)sx, y0 = (int)sy, z0 = (int)sz;
        const int x1 = min(x0 + 1, GH - 1);
        const int y1 = min(y0 + 1, GW - 1);
        const int z1 = min(z0 + 1, GD - 1);
        const float wx = sx - x0, wy = sy - y0, wz = sz - z0;
        const float* p00 = grid + ((size_t)x0 * GW + (size_t)y0) * GD;
        const float* p01 = grid + ((size_t)x0 * GW + (size_t)y1) * GD;
        const float* p10 = grid + ((size_t)x1 * GW + (size_t)y0) * GD;
        const float* p11 = grid + ((size_t)x1 * GW + (size_t)y1) * GD;
        const float c00 = p00[z0] * (1 - wz) + p00[z1] * wz;
        const float c01 = p01[z0] * (1 - wz) + p01[z1] * wz;
        const float c10 = p10[z0] * (1 - wz) + p10[z1] * wz;
        const float c11 = p11[z0] * (1 - wz) + p11[z1] * wz;
        const float c0 = c00 * (1 - wy) + c01 * wy;
        const float c1 = c10 * (1 - wy) + c11 * wy;
        val = c0 * (1 - wx) + c1 * wx;
        out[1 + i] = val;
    }
    float s = val;
    #pragma unroll
    for (int off = 32; off > 0; off >>= 1) s += __shfl_down(s, off, 64);
    __shared__ float wsum[4];
    if ((threadIdx.x & 63) == 0) wsum[threadIdx.x >> 6] = s;
    __syncthreads();
    if (threadIdx.x == 0)
        atomicAdd(out, (wsum[0] + wsum[1] + wsum[2] + wsum[3]) * (1.0f / (float)N));
}

extern "C" void kernel_launch(void* const* d_in, const int* in_sizes, int n_in,
                              void* d_out, int out_size, void* d_ws, size_t ws_size,
                              hipStream_t stream) {
    const float* pc1         = (const float*)d_in[0];
    const float* flow        = (const float*)d_in[1];
    const float* grid        = (const float*)d_in[2];
    const float* grid_min    = (const float*)d_in[3];
    const int*   grid_factor = (const int*)d_in[4];
    float* out = (float*)d_out;

    const int N = in_sizes[0] / 3;  // pc1 is [1, N, 3]
    hipMemsetAsync(d_out, 0, sizeof(float), stream);

    if ((N & 3) != 0) {
        dt_loss_direct<<<(N + 255) / 256, 256, 0, stream>>>(
            pc1, flow, grid, grid_min, grid_factor, out, N);
        return;
    }

    const int nb = (N + TILE - 1) / TILE;
    dt_loss_zwin<<<nb, 256, 0, stream>>>(
        pc1, flow, grid, grid_min, grid_factor, out, N);
}